// Round 4
// baseline (502.641 us; speedup 1.0000x reference)
//
#include <hip/hip_runtime.h>

#define HW 65536
#define W_IMG 256
#define H_IMG 256
#define CIN 64
#define CHID 384
#define CQK 128

// ---------------- K1: 1x1 expansion GEMM (wave-uniform weight broadcast) ----------------
// block = 64co x 256px, 4 waves; wave owns 16co x 256px; lane owns 16co x 4px.
// Weight LDS reads are wave-uniform (broadcast, ~free); only x reads hit banks.
__global__ __launch_bounds__(256) void k1_expand(
    const float* __restrict__ x_base,    // [B][CIN][HW]
    const float* __restrict__ wh,        // [CHID][CIN]
    const float* __restrict__ bh,        // [CHID]
    float* __restrict__ hidden_base,     // [B][CHID][HW]
    size_t x_bstride, size_t hid_bstride)
{
    __shared__ float xs[CIN][256];       // 64 KB
    __shared__ float wst[CIN][64];       // 16 KB, [ci][co]
    const float* x = x_base + blockIdx.z * x_bstride;
    float* hidden  = hidden_base + blockIdx.z * hid_bstride;
    const int cobase = blockIdx.x * 64;   // co fastest -> px-tile L2 reuse across co-blocks
    const int pxbase = blockIdx.y * 256;
    const int tid = threadIdx.x;

    // stage x tile: 64ci x 256px = 4096 float4, 16/thread, fully coalesced
    #pragma unroll
    for (int it = 0; it < 16; ++it) {
        int f4 = it * 256 + tid;
        int ci = f4 >> 6;
        int p4 = f4 & 63;
        *reinterpret_cast<float4*>(&xs[ci][p4 * 4]) =
            *reinterpret_cast<const float4*>(&x[(size_t)ci * HW + pxbase + p4 * 4]);
    }
    // stage weights transposed [ci][co] (wh is L1/L2-resident, 98 KB total)
    #pragma unroll
    for (int it = 0; it < 16; ++it) {
        int idx = it * 256 + tid;
        int ci = idx >> 6;
        int co = idx & 63;
        wst[ci][co] = wh[(size_t)(cobase + co) * CIN + ci];
    }
    __syncthreads();

    const int lane = tid & 63;
    const int wq   = tid >> 6;           // wave 0..3
    const int px0  = lane * 4;
    const int cw   = wq * 16;            // wave's co offset

    float acc[16][4];
    #pragma unroll
    for (int i = 0; i < 16; ++i)
        #pragma unroll
        for (int j = 0; j < 4; ++j) acc[i][j] = 0.f;

    #pragma unroll 4
    for (int ci = 0; ci < CIN; ++ci) {
        float4 xv = *reinterpret_cast<const float4*>(&xs[ci][px0]);
        float4 w0 = *reinterpret_cast<const float4*>(&wst[ci][cw]);      // broadcast
        float4 w1 = *reinterpret_cast<const float4*>(&wst[ci][cw + 4]);  // broadcast
        float4 w2 = *reinterpret_cast<const float4*>(&wst[ci][cw + 8]);  // broadcast
        float4 w3 = *reinterpret_cast<const float4*>(&wst[ci][cw + 12]); // broadcast
        float wr[16] = {w0.x, w0.y, w0.z, w0.w, w1.x, w1.y, w1.z, w1.w,
                        w2.x, w2.y, w2.z, w2.w, w3.x, w3.y, w3.z, w3.w};
        #pragma unroll
        for (int i = 0; i < 16; ++i) {
            acc[i][0] += wr[i] * xv.x;
            acc[i][1] += wr[i] * xv.y;
            acc[i][2] += wr[i] * xv.z;
            acc[i][3] += wr[i] * xv.w;
        }
    }

    #pragma unroll
    for (int i = 0; i < 16; ++i) {
        int co = cobase + cw + i;
        float b = bh[co];
        float4 o;
        o.x = acc[i][0] + b; o.y = acc[i][1] + b;
        o.z = acc[i][2] + b; o.w = acc[i][3] + b;
        *reinterpret_cast<float4*>(&hidden[(size_t)co * HW + pxbase + px0]) = o;
    }
}

// ---------------- K2: fused depthwise 3x3 + 8x8 circular conv + v-mul ----------------
__global__ __launch_bounds__(256) void k2_fused(
    const float* __restrict__ hidden_base,  // [B][CHID][HW]
    const float* __restrict__ wdw,          // [CHID][9]
    const float* __restrict__ bdw,          // [CHID]
    float* __restrict__ vout_base,          // [B][CQK][HW]
    size_t hid_bstride, size_t vout_bstride)
{
    __shared__ float stg[2][10][260];
    __shared__ float qk[2][8][4][68];

    const float* hidden = hidden_base + blockIdx.z * hid_bstride;
    float* vout         = vout_base + blockIdx.z * vout_bstride;

    const int c  = blockIdx.y;
    const int r0 = blockIdx.x * 8;
    const int tid = threadIdx.x;

    #pragma unroll
    for (int it = 0; it < 5; ++it) {
        int f4  = it * 256 + tid;
        int ch  = f4 / 640;
        int rem = f4 - ch * 640;
        int lr  = rem >> 6;
        int p4  = rem & 63;
        int gr  = r0 - 1 + lr;
        float4 v = make_float4(0.f, 0.f, 0.f, 0.f);
        if ((unsigned)gr < H_IMG)
            v = *reinterpret_cast<const float4*>(
                &hidden[(size_t)(c + ch * CQK) * HW + (size_t)gr * W_IMG + p4 * 4]);
        *reinterpret_cast<float4*>(&stg[ch][lr][p4 * 4]) = v;
    }
    __syncthreads();

    const int w = tid;
    const int segw = w >> 6;
    const int tw   = w & 63;
    #pragma unroll
    for (int ch = 0; ch < 2; ++ch) {
        const float* wv = wdw + (c + ch * CQK) * 9;
        const float bias = bdw[c + ch * CQK];
        const float w0 = wv[0], w1 = wv[1], w2 = wv[2];
        const float w3 = wv[3], w4 = wv[4], w5 = wv[5];
        const float w6 = wv[6], w7 = wv[7], w8 = wv[8];
        const float* S = &stg[ch][0][0];

        float am, a0, ap, bm, b0, bp;
        a0 = S[w];
        am = (w > 0)   ? S[w - 1] : 0.f;
        ap = (w < 255) ? S[w + 1] : 0.f;
        b0 = S[260 + w];
        bm = (w > 0)   ? S[260 + w - 1] : 0.f;
        bp = (w < 255) ? S[260 + w + 1] : 0.f;

        #pragma unroll
        for (int r = 0; r < 8; ++r) {
            const float* Sr = S + (r + 2) * 260;
            float c0 = Sr[w];
            float cm = (w > 0)   ? Sr[w - 1] : 0.f;
            float cp = (w < 255) ? Sr[w + 1] : 0.f;
            float a = bias + am * w0 + a0 * w1 + ap * w2
                           + bm * w3 + b0 * w4 + bp * w5
                           + cm * w6 + c0 * w7 + cp * w8;
            qk[ch][r][segw][tw] = a;
            am = bm; a0 = b0; ap = bp;
            bm = cm; b0 = c0; bp = cp;
        }
    }
    __syncthreads();

    const int row = tid >> 5;
    const int seg = (tid >> 3) & 3;
    const int i   = tid & 7;
    const int gr  = r0 + row;
    const int wp0 = seg * 64 + i * 8;

    const float* hbv = hidden + (size_t)(c + 2 * CQK) * HW;
    float4 hv[3][2];
    float  hm[3], hp[3];
    #pragma unroll
    for (int ky = 0; ky < 3; ++ky) {
        int grr = gr + ky - 1;
        hv[ky][0] = make_float4(0.f, 0.f, 0.f, 0.f);
        hv[ky][1] = make_float4(0.f, 0.f, 0.f, 0.f);
        hm[ky] = 0.f; hp[ky] = 0.f;
        if ((unsigned)grr < H_IMG) {
            const float* rb = hbv + (size_t)grr * W_IMG;
            hv[ky][0] = *reinterpret_cast<const float4*>(&rb[wp0]);
            hv[ky][1] = *reinterpret_cast<const float4*>(&rb[wp0 + 4]);
            hm[ky] = (wp0 > 0)   ? rb[wp0 - 1] : 0.f;
            hp[ky] = (wp0 < 248) ? rb[wp0 + 8] : 0.f;
        }
    }

    const float* qb = &qk[0][row][seg][0];
    const float* kb = &qk[1][row][seg][0];

    float acc[8];
    #pragma unroll
    for (int j = 0; j < 8; ++j) acc[j] = 0.f;

    #pragma unroll
    for (int s = 0; s < 8; ++s) {
        int qr = (i - s) & 7;
        float4 ka = *reinterpret_cast<const float4*>(&kb[s * 8]);
        float4 kc = *reinterpret_cast<const float4*>(&kb[s * 8 + 4]);
        float4 qa = *reinterpret_cast<const float4*>(&qb[qr * 8]);
        float4 qc = *reinterpret_cast<const float4*>(&qb[qr * 8 + 4]);
        float kr[8] = {ka.x, ka.y, ka.z, ka.w, kc.x, kc.y, kc.z, kc.w};
        float qv[8] = {qa.x, qa.y, qa.z, qa.w, qc.x, qc.y, qc.z, qc.w};
        #pragma unroll
        for (int t = 0; t < 8; ++t)
            #pragma unroll
            for (int j = 0; j < 8; ++j)
                acc[j] += kr[t] * qv[(j - t) & 7];
    }

    const float* wvv = wdw + (c + 2 * CQK) * 9;
    const float vbias = bdw[c + 2 * CQK];
    float vc[8];
    #pragma unroll
    for (int j = 0; j < 8; ++j) vc[j] = vbias;
    #pragma unroll
    for (int ky = 0; ky < 3; ++ky) {
        float kw0 = wvv[ky * 3], kw1 = wvv[ky * 3 + 1], kw2 = wvv[ky * 3 + 2];
        float h[10];
        h[0] = hm[ky];
        h[1] = hv[ky][0].x; h[2] = hv[ky][0].y; h[3] = hv[ky][0].z; h[4] = hv[ky][0].w;
        h[5] = hv[ky][1].x; h[6] = hv[ky][1].y; h[7] = hv[ky][1].z; h[8] = hv[ky][1].w;
        h[9] = hp[ky];
        #pragma unroll
        for (int j = 0; j < 8; ++j)
            vc[j] += h[j] * kw0 + h[j + 1] * kw1 + h[j + 2] * kw2;
    }

    float* dst = &vout[(size_t)c * HW + (size_t)gr * W_IMG + wp0];
    float4 o0, o1;
    o0.x = acc[0] * vc[0]; o0.y = acc[1] * vc[1];
    o0.z = acc[2] * vc[2]; o0.w = acc[3] * vc[3];
    o1.x = acc[4] * vc[4]; o1.y = acc[5] * vc[5];
    o1.z = acc[6] * vc[6]; o1.w = acc[7] * vc[7];
    *reinterpret_cast<float4*>(dst)     = o0;
    *reinterpret_cast<float4*>(dst + 4) = o1;
}

// ---------------- K3: 1x1 projection GEMM (wave-uniform weight broadcast) ----------------
// block = 64co x 64px, 4 waves; wave owns 16co x 64px; lane owns 16co x 1px.
__global__ __launch_bounds__(256) void k3_project(
    const float* __restrict__ vout_base,  // [B][CQK][HW]
    const float* __restrict__ wo,         // [64][CQK]
    const float* __restrict__ bo,         // [64]
    float* __restrict__ out_base,         // [B][64][HW]
    size_t vout_bstride, size_t out_bstride)
{
    __shared__ float vsh[CQK][64];       // 32 KB
    __shared__ float wsh[CQK][64];       // 32 KB, [cc][co]
    const float* vout = vout_base + blockIdx.z * vout_bstride;
    float* out        = out_base + blockIdx.z * out_bstride;
    const int pxbase = blockIdx.x * 64;
    const int tid = threadIdx.x;

    #pragma unroll
    for (int it = 0; it < 8; ++it) {
        int f4 = it * 256 + tid;
        int cc = f4 >> 4;
        int p4 = f4 & 15;
        *reinterpret_cast<float4*>(&vsh[cc][p4 * 4]) =
            *reinterpret_cast<const float4*>(&vout[(size_t)cc * HW + pxbase + p4 * 4]);
    }
    #pragma unroll
    for (int it = 0; it < 32; ++it) {
        int idx = it * 256 + tid;
        int cc = idx >> 6;
        int co = idx & 63;
        wsh[cc][co] = wo[(size_t)co * CQK + cc];
    }
    __syncthreads();

    const int lane = tid & 63;
    const int wq   = tid >> 6;
    const int cw   = wq * 16;

    float acc[16];
    #pragma unroll
    for (int i = 0; i < 16; ++i) acc[i] = 0.f;

    #pragma unroll 8
    for (int cc = 0; cc < CQK; ++cc) {
        float xv = vsh[cc][lane];
        float4 w0 = *reinterpret_cast<const float4*>(&wsh[cc][cw]);      // broadcast
        float4 w1 = *reinterpret_cast<const float4*>(&wsh[cc][cw + 4]);  // broadcast
        float4 w2 = *reinterpret_cast<const float4*>(&wsh[cc][cw + 8]);  // broadcast
        float4 w3 = *reinterpret_cast<const float4*>(&wsh[cc][cw + 12]); // broadcast
        float wr[16] = {w0.x, w0.y, w0.z, w0.w, w1.x, w1.y, w1.z, w1.w,
                        w2.x, w2.y, w2.z, w2.w, w3.x, w3.y, w3.z, w3.w};
        #pragma unroll
        for (int i = 0; i < 16; ++i) acc[i] += wr[i] * xv;
    }

    #pragma unroll
    for (int i = 0; i < 16; ++i) {
        int co = cw + i;
        out[(size_t)co * HW + pxbase + lane] = acc[i] + bo[co];
    }
}

extern "C" void kernel_launch(void* const* d_in, const int* in_sizes, int n_in,
                              void* d_out, int out_size, void* d_ws, size_t ws_size,
                              hipStream_t stream) {
    const float* x   = (const float*)d_in[0];
    const float* wh  = (const float*)d_in[1];
    const float* bh  = (const float*)d_in[2];
    const float* wdw = (const float*)d_in[3];
    const float* bdw = (const float*)d_in[4];
    const float* wo  = (const float*)d_in[5];
    const float* bo  = (const float*)d_in[6];
    float* out = (float*)d_out;

    const size_t n_hid  = (size_t)CHID * HW;
    const size_t n_vout = (size_t)CQK * HW;
    const size_t n_x    = (size_t)CIN * HW;

    if (ws_size >= 4 * (n_hid + n_vout) * sizeof(float)) {
        float* hidden = (float*)d_ws;
        float* vout   = hidden + 4 * n_hid;
        k1_expand <<<dim3(CHID / 64, HW / 256, 4), 256, 0, stream>>>(
            x, wh, bh, hidden, n_x, n_hid);
        k2_fused  <<<dim3(H_IMG / 8, CQK, 4),      256, 0, stream>>>(
            hidden, wdw, bdw, vout, n_hid, n_vout);
        k3_project<<<dim3(HW / 64, 1, 4),          256, 0, stream>>>(
            vout, wo, bo, out, n_vout, n_x);
    } else {
        float* hidden = (float*)d_ws;
        float* vout   = hidden + n_hid;
        for (int b = 0; b < 4; ++b) {
            const float* xb = x + (size_t)b * n_x;
            float* ob       = out + (size_t)b * n_x;
            k1_expand <<<dim3(CHID / 64, HW / 256, 1), 256, 0, stream>>>(
                xb, wh, bh, hidden, 0, 0);
            k2_fused  <<<dim3(H_IMG / 8, CQK, 1),      256, 0, stream>>>(
                hidden, wdw, bdw, vout, 0, 0);
            k3_project<<<dim3(HW / 64, 1, 1),          256, 0, stream>>>(
                vout, wo, bo, ob, 0, 0);
        }
    }
}

// Round 5
// 464.181 us; speedup vs baseline: 1.0829x; 1.0829x over previous
//
#include <hip/hip_runtime.h>

#define HW 65536
#define W_IMG 256
#define H_IMG 256
#define CIN 64
#define CHID 384
#define CQK 128

// ---------------- K1: 1x1 expansion GEMM ----------------
// block = 64co x 256px, 4 waves; wave owns 16co x 256px; lane owns 16co x 4px.
// Weights read via wave-uniform (readfirstlane-scalarized) pointers -> SMEM/L1
// broadcast, no LDS. x staged in two 32-ci halves (32 KB LDS -> 4 blocks/CU).
__global__ __launch_bounds__(256) void k1_expand(
    const float* __restrict__ x_base,    // [B][CIN][HW]
    const float* __restrict__ wh,        // [CHID][CIN]
    const float* __restrict__ bh,        // [CHID]
    float* __restrict__ hidden_base,     // [B][CHID][HW]
    size_t x_bstride, size_t hid_bstride)
{
    __shared__ float xs[32][256];        // 32 KB
    const float* x = x_base + blockIdx.z * x_bstride;
    float* hidden  = hidden_base + blockIdx.z * hid_bstride;
    const int pxbase = blockIdx.x * 256; // px fastest (R3 order: good L3 behavior)
    const int cobase = blockIdx.y * 64;
    const int tid  = threadIdx.x;
    const int lane = tid & 63;
    const int wq   = __builtin_amdgcn_readfirstlane(tid >> 6);  // wave id, scalar
    const int px0  = lane * 4;
    const int cw   = cobase + wq * 16;   // wave's first co (wave-uniform scalar)

    float acc[16][4];
    #pragma unroll
    for (int i = 0; i < 16; ++i)
        #pragma unroll
        for (int j = 0; j < 4; ++j) acc[i][j] = 0.f;

    #pragma unroll
    for (int half = 0; half < 2; ++half) {
        const int cib = half * 32;
        if (half) __syncthreads();       // prev compute done before overwrite
        // stage 32ci x 256px (2048 float4, 8/thread, coalesced)
        #pragma unroll
        for (int it = 0; it < 8; ++it) {
            int f4 = it * 256 + tid;
            int ci = f4 >> 6;
            int p4 = f4 & 63;
            *reinterpret_cast<float4*>(&xs[ci][p4 * 4]) =
                *reinterpret_cast<const float4*>(
                    &x[(size_t)(cib + ci) * HW + pxbase + p4 * 4]);
        }
        __syncthreads();

        for (int ci4 = 0; ci4 < 32; ci4 += 4) {
            float4 xv[4];
            #pragma unroll
            for (int u = 0; u < 4; ++u)
                xv[u] = *reinterpret_cast<const float4*>(&xs[ci4 + u][px0]);
            #pragma unroll
            for (int g = 0; g < 4; ++g) {
                #pragma unroll
                for (int i = 0; i < 4; ++i) {
                    // wave-uniform address -> scalar load (float4 along ci)
                    float4 wv = *reinterpret_cast<const float4*>(
                        &wh[(size_t)(cw + g * 4 + i) * CIN + cib + ci4]);
                    float wu[4] = {wv.x, wv.y, wv.z, wv.w};
                    #pragma unroll
                    for (int u = 0; u < 4; ++u) {
                        acc[g * 4 + i][0] += wu[u] * xv[u].x;
                        acc[g * 4 + i][1] += wu[u] * xv[u].y;
                        acc[g * 4 + i][2] += wu[u] * xv[u].z;
                        acc[g * 4 + i][3] += wu[u] * xv[u].w;
                    }
                }
            }
        }
    }

    #pragma unroll
    for (int i = 0; i < 16; ++i) {
        int co = cw + i;
        float b = bh[co];
        float4 o;
        o.x = acc[i][0] + b; o.y = acc[i][1] + b;
        o.z = acc[i][2] + b; o.w = acc[i][3] + b;
        *reinterpret_cast<float4*>(&hidden[(size_t)co * HW + pxbase + px0]) = o;
    }
}

// ---------------- K2: fused depthwise 3x3 + 8x8 circular conv + v-mul ----------------
__global__ __launch_bounds__(256) void k2_fused(
    const float* __restrict__ hidden_base,  // [B][CHID][HW]
    const float* __restrict__ wdw,          // [CHID][9]
    const float* __restrict__ bdw,          // [CHID]
    float* __restrict__ vout_base,          // [B][CQK][HW]
    size_t hid_bstride, size_t vout_bstride)
{
    __shared__ float stg[2][10][260];
    __shared__ float qk[2][8][4][68];

    const float* hidden = hidden_base + blockIdx.z * hid_bstride;
    float* vout         = vout_base + blockIdx.z * vout_bstride;

    const int c  = blockIdx.y;
    const int r0 = blockIdx.x * 8;
    const int tid = threadIdx.x;

    #pragma unroll
    for (int it = 0; it < 5; ++it) {
        int f4  = it * 256 + tid;
        int ch  = f4 / 640;
        int rem = f4 - ch * 640;
        int lr  = rem >> 6;
        int p4  = rem & 63;
        int gr  = r0 - 1 + lr;
        float4 v = make_float4(0.f, 0.f, 0.f, 0.f);
        if ((unsigned)gr < H_IMG)
            v = *reinterpret_cast<const float4*>(
                &hidden[(size_t)(c + ch * CQK) * HW + (size_t)gr * W_IMG + p4 * 4]);
        *reinterpret_cast<float4*>(&stg[ch][lr][p4 * 4]) = v;
    }
    __syncthreads();

    const int w = tid;
    const int segw = w >> 6;
    const int tw   = w & 63;
    #pragma unroll
    for (int ch = 0; ch < 2; ++ch) {
        const float* wv = wdw + (c + ch * CQK) * 9;
        const float bias = bdw[c + ch * CQK];
        const float w0 = wv[0], w1 = wv[1], w2 = wv[2];
        const float w3 = wv[3], w4 = wv[4], w5 = wv[5];
        const float w6 = wv[6], w7 = wv[7], w8 = wv[8];
        const float* S = &stg[ch][0][0];

        float am, a0, ap, bm, b0, bp;
        a0 = S[w];
        am = (w > 0)   ? S[w - 1] : 0.f;
        ap = (w < 255) ? S[w + 1] : 0.f;
        b0 = S[260 + w];
        bm = (w > 0)   ? S[260 + w - 1] : 0.f;
        bp = (w < 255) ? S[260 + w + 1] : 0.f;

        #pragma unroll
        for (int r = 0; r < 8; ++r) {
            const float* Sr = S + (r + 2) * 260;
            float c0 = Sr[w];
            float cm = (w > 0)   ? Sr[w - 1] : 0.f;
            float cp = (w < 255) ? Sr[w + 1] : 0.f;
            float a = bias + am * w0 + a0 * w1 + ap * w2
                           + bm * w3 + b0 * w4 + bp * w5
                           + cm * w6 + c0 * w7 + cp * w8;
            qk[ch][r][segw][tw] = a;
            am = bm; a0 = b0; ap = bp;
            bm = cm; b0 = c0; bp = cp;
        }
    }
    __syncthreads();

    const int row = tid >> 5;
    const int seg = (tid >> 3) & 3;
    const int i   = tid & 7;
    const int gr  = r0 + row;
    const int wp0 = seg * 64 + i * 8;

    const float* hbv = hidden + (size_t)(c + 2 * CQK) * HW;
    float4 hv[3][2];
    float  hm[3], hp[3];
    #pragma unroll
    for (int ky = 0; ky < 3; ++ky) {
        int grr = gr + ky - 1;
        hv[ky][0] = make_float4(0.f, 0.f, 0.f, 0.f);
        hv[ky][1] = make_float4(0.f, 0.f, 0.f, 0.f);
        hm[ky] = 0.f; hp[ky] = 0.f;
        if ((unsigned)grr < H_IMG) {
            const float* rb = hbv + (size_t)grr * W_IMG;
            hv[ky][0] = *reinterpret_cast<const float4*>(&rb[wp0]);
            hv[ky][1] = *reinterpret_cast<const float4*>(&rb[wp0 + 4]);
            hm[ky] = (wp0 > 0)   ? rb[wp0 - 1] : 0.f;
            hp[ky] = (wp0 < 248) ? rb[wp0 + 8] : 0.f;
        }
    }

    const float* qb = &qk[0][row][seg][0];
    const float* kb = &qk[1][row][seg][0];

    float acc[8];
    #pragma unroll
    for (int j = 0; j < 8; ++j) acc[j] = 0.f;

    #pragma unroll
    for (int s = 0; s < 8; ++s) {
        int qr = (i - s) & 7;
        float4 ka = *reinterpret_cast<const float4*>(&kb[s * 8]);
        float4 kc = *reinterpret_cast<const float4*>(&kb[s * 8 + 4]);
        float4 qa = *reinterpret_cast<const float4*>(&qb[qr * 8]);
        float4 qc = *reinterpret_cast<const float4*>(&qb[qr * 8 + 4]);
        float kr[8] = {ka.x, ka.y, ka.z, ka.w, kc.x, kc.y, kc.z, kc.w};
        float qv[8] = {qa.x, qa.y, qa.z, qa.w, qc.x, qc.y, qc.z, qc.w};
        #pragma unroll
        for (int t = 0; t < 8; ++t)
            #pragma unroll
            for (int j = 0; j < 8; ++j)
                acc[j] += kr[t] * qv[(j - t) & 7];
    }

    const float* wvv = wdw + (c + 2 * CQK) * 9;
    const float vbias = bdw[c + 2 * CQK];
    float vc[8];
    #pragma unroll
    for (int j = 0; j < 8; ++j) vc[j] = vbias;
    #pragma unroll
    for (int ky = 0; ky < 3; ++ky) {
        float kw0 = wvv[ky * 3], kw1 = wvv[ky * 3 + 1], kw2 = wvv[ky * 3 + 2];
        float h[10];
        h[0] = hm[ky];
        h[1] = hv[ky][0].x; h[2] = hv[ky][0].y; h[3] = hv[ky][0].z; h[4] = hv[ky][0].w;
        h[5] = hv[ky][1].x; h[6] = hv[ky][1].y; h[7] = hv[ky][1].z; h[8] = hv[ky][1].w;
        h[9] = hp[ky];
        #pragma unroll
        for (int j = 0; j < 8; ++j)
            vc[j] += h[j] * kw0 + h[j + 1] * kw1 + h[j + 2] * kw2;
    }

    float* dst = &vout[(size_t)c * HW + (size_t)gr * W_IMG + wp0];
    float4 o0, o1;
    o0.x = acc[0] * vc[0]; o0.y = acc[1] * vc[1];
    o0.z = acc[2] * vc[2]; o0.w = acc[3] * vc[3];
    o1.x = acc[4] * vc[4]; o1.y = acc[5] * vc[5];
    o1.z = acc[6] * vc[6]; o1.w = acc[7] * vc[7];
    *reinterpret_cast<float4*>(dst)     = o0;
    *reinterpret_cast<float4*>(dst + 4) = o1;
}

// ---------------- K3: 1x1 projection GEMM ----------------
// block = 64co x 64px, 4 waves; wave owns 16co x 64px; lane owns 16co x 1px.
// Weights via wave-uniform scalar loads (native [co][cc] layout, float4 along cc).
__global__ __launch_bounds__(256) void k3_project(
    const float* __restrict__ vout_base,  // [B][CQK][HW]
    const float* __restrict__ wo,         // [64][CQK]
    const float* __restrict__ bo,         // [64]
    float* __restrict__ out_base,         // [B][64][HW]
    size_t vout_bstride, size_t out_bstride)
{
    __shared__ float vsh[CQK][64];       // 32 KB
    const float* vout = vout_base + blockIdx.z * vout_bstride;
    float* out        = out_base + blockIdx.z * out_bstride;
    const int pxbase = blockIdx.x * 64;
    const int tid  = threadIdx.x;
    const int lane = tid & 63;
    const int wq   = __builtin_amdgcn_readfirstlane(tid >> 6);
    const int cw   = wq * 16;

    #pragma unroll
    for (int it = 0; it < 8; ++it) {
        int f4 = it * 256 + tid;
        int cc = f4 >> 4;
        int p4 = f4 & 15;
        *reinterpret_cast<float4*>(&vsh[cc][p4 * 4]) =
            *reinterpret_cast<const float4*>(&vout[(size_t)cc * HW + pxbase + p4 * 4]);
    }
    __syncthreads();

    float acc[16];
    #pragma unroll
    for (int i = 0; i < 16; ++i) acc[i] = 0.f;

    for (int cc4 = 0; cc4 < CQK; cc4 += 4) {
        float xv[4];
        #pragma unroll
        for (int u = 0; u < 4; ++u)
            xv[u] = vsh[cc4 + u][lane];
        #pragma unroll
        for (int g = 0; g < 4; ++g) {
            #pragma unroll
            for (int i = 0; i < 4; ++i) {
                float4 wv = *reinterpret_cast<const float4*>(
                    &wo[(size_t)(cw + g * 4 + i) * CQK + cc4]);   // uniform -> scalar
                acc[g * 4 + i] += wv.x * xv[0] + wv.y * xv[1]
                                + wv.z * xv[2] + wv.w * xv[3];
            }
        }
    }

    #pragma unroll
    for (int i = 0; i < 16; ++i) {
        int co = cw + i;
        out[(size_t)co * HW + pxbase + lane] = acc[i] + bo[co];
    }
}

extern "C" void kernel_launch(void* const* d_in, const int* in_sizes, int n_in,
                              void* d_out, int out_size, void* d_ws, size_t ws_size,
                              hipStream_t stream) {
    const float* x   = (const float*)d_in[0];
    const float* wh  = (const float*)d_in[1];
    const float* bh  = (const float*)d_in[2];
    const float* wdw = (const float*)d_in[3];
    const float* bdw = (const float*)d_in[4];
    const float* wo  = (const float*)d_in[5];
    const float* bo  = (const float*)d_in[6];
    float* out = (float*)d_out;

    const size_t n_hid  = (size_t)CHID * HW;
    const size_t n_vout = (size_t)CQK * HW;
    const size_t n_x    = (size_t)CIN * HW;

    if (ws_size >= 4 * (n_hid + n_vout) * sizeof(float)) {
        float* hidden = (float*)d_ws;
        float* vout   = hidden + 4 * n_hid;
        k1_expand <<<dim3(HW / 256, CHID / 64, 4), 256, 0, stream>>>(
            x, wh, bh, hidden, n_x, n_hid);
        k2_fused  <<<dim3(H_IMG / 8, CQK, 4),      256, 0, stream>>>(
            hidden, wdw, bdw, vout, n_hid, n_vout);
        k3_project<<<dim3(HW / 64, 1, 4),          256, 0, stream>>>(
            vout, wo, bo, out, n_vout, n_x);
    } else {
        float* hidden = (float*)d_ws;
        float* vout   = hidden + n_hid;
        for (int b = 0; b < 4; ++b) {
            const float* xb = x + (size_t)b * n_x;
            float* ob       = out + (size_t)b * n_x;
            k1_expand <<<dim3(HW / 256, CHID / 64, 1), 256, 0, stream>>>(
                xb, wh, bh, hidden, 0, 0);
            k2_fused  <<<dim3(H_IMG / 8, CQK, 1),      256, 0, stream>>>(
                hidden, wdw, bdw, vout, 0, 0);
            k3_project<<<dim3(HW / 64, 1, 1),          256, 0, stream>>>(
                vout, wo, bo, ob, 0, 0);
        }
    }
}

// Round 6
// 420.088 us; speedup vs baseline: 1.1965x; 1.1050x over previous
//
#include <hip/hip_runtime.h>

#define HW 65536
#define W_IMG 256
#define H_IMG 256
#define CIN 64
#define CHID 384
#define CQK 128

// ---------------- K1: 1x1 expansion GEMM (LDS-free streaming) ----------------
// block = 64co x 256px, 4 waves; wave owns 16co x 256px; lane owns 16co x 4px.
// x read directly from global (float4, vmcnt domain); weights via wave-uniform
// scalar loads (SGPR, lgkmcnt domain) -> the two streams never cross-stall.
__global__ __launch_bounds__(256) void k1_expand(
    const float* __restrict__ x_base,    // [B][CIN][HW]
    const float* __restrict__ wh,        // [CHID][CIN]
    const float* __restrict__ bh,        // [CHID]
    float* __restrict__ hidden_base,     // [B][CHID][HW]
    size_t x_bstride, size_t hid_bstride)
{
    const float* x = x_base + blockIdx.z * x_bstride;
    float* hidden  = hidden_base + blockIdx.z * hid_bstride;
    const int pxbase = blockIdx.x * 256;
    const int cobase = blockIdx.y * 64;
    const int tid  = threadIdx.x;
    const int lane = tid & 63;
    const int wq   = __builtin_amdgcn_readfirstlane(tid >> 6);
    const int px   = pxbase + lane * 4;
    const int cw   = cobase + wq * 16;    // wave-uniform

    float acc[16][4];
    #pragma unroll
    for (int i = 0; i < 16; ++i)
        #pragma unroll
        for (int j = 0; j < 4; ++j) acc[i][j] = 0.f;

    #pragma unroll 2
    for (int ci4 = 0; ci4 < CIN; ci4 += 4) {
        float4 xv[4];
        #pragma unroll
        for (int u = 0; u < 4; ++u)
            xv[u] = *reinterpret_cast<const float4*>(&x[(size_t)(ci4 + u) * HW + px]);
        #pragma unroll
        for (int i = 0; i < 16; ++i) {
            // wave-uniform address -> s_load_dwordx4 (SGPR weights)
            float4 wv = *reinterpret_cast<const float4*>(
                &wh[(size_t)(cw + i) * CIN + ci4]);
            float wu[4] = {wv.x, wv.y, wv.z, wv.w};
            #pragma unroll
            for (int u = 0; u < 4; ++u) {
                acc[i][0] += wu[u] * xv[u].x;
                acc[i][1] += wu[u] * xv[u].y;
                acc[i][2] += wu[u] * xv[u].z;
                acc[i][3] += wu[u] * xv[u].w;
            }
        }
    }

    #pragma unroll
    for (int i = 0; i < 16; ++i) {
        int co = cw + i;
        float b = bh[co];
        float4 o;
        o.x = acc[i][0] + b; o.y = acc[i][1] + b;
        o.z = acc[i][2] + b; o.w = acc[i][3] + b;
        *reinterpret_cast<float4*>(&hidden[(size_t)co * HW + px]) = o;
    }
}

// ---------------- K2: fused depthwise 3x3 + 8x8 circular conv + v-mul ----------------
__global__ __launch_bounds__(256) void k2_fused(
    const float* __restrict__ hidden_base,  // [B][CHID][HW]
    const float* __restrict__ wdw,          // [CHID][9]
    const float* __restrict__ bdw,          // [CHID]
    float* __restrict__ vout_base,          // [B][CQK][HW]
    size_t hid_bstride, size_t vout_bstride)
{
    __shared__ float stg[2][10][260];
    __shared__ float qk[2][8][4][68];

    const float* hidden = hidden_base + blockIdx.z * hid_bstride;
    float* vout         = vout_base + blockIdx.z * vout_bstride;

    const int c  = blockIdx.y;
    const int r0 = blockIdx.x * 8;
    const int tid = threadIdx.x;

    #pragma unroll
    for (int it = 0; it < 5; ++it) {
        int f4  = it * 256 + tid;
        int ch  = f4 / 640;
        int rem = f4 - ch * 640;
        int lr  = rem >> 6;
        int p4  = rem & 63;
        int gr  = r0 - 1 + lr;
        float4 v = make_float4(0.f, 0.f, 0.f, 0.f);
        if ((unsigned)gr < H_IMG)
            v = *reinterpret_cast<const float4*>(
                &hidden[(size_t)(c + ch * CQK) * HW + (size_t)gr * W_IMG + p4 * 4]);
        *reinterpret_cast<float4*>(&stg[ch][lr][p4 * 4]) = v;
    }
    __syncthreads();

    const int w = tid;
    const int segw = w >> 6;
    const int tw   = w & 63;
    #pragma unroll
    for (int ch = 0; ch < 2; ++ch) {
        const float* wv = wdw + (c + ch * CQK) * 9;
        const float bias = bdw[c + ch * CQK];
        const float w0 = wv[0], w1 = wv[1], w2 = wv[2];
        const float w3 = wv[3], w4 = wv[4], w5 = wv[5];
        const float w6 = wv[6], w7 = wv[7], w8 = wv[8];
        const float* S = &stg[ch][0][0];

        float am, a0, ap, bm, b0, bp;
        a0 = S[w];
        am = (w > 0)   ? S[w - 1] : 0.f;
        ap = (w < 255) ? S[w + 1] : 0.f;
        b0 = S[260 + w];
        bm = (w > 0)   ? S[260 + w - 1] : 0.f;
        bp = (w < 255) ? S[260 + w + 1] : 0.f;

        #pragma unroll
        for (int r = 0; r < 8; ++r) {
            const float* Sr = S + (r + 2) * 260;
            float c0 = Sr[w];
            float cm = (w > 0)   ? Sr[w - 1] : 0.f;
            float cp = (w < 255) ? Sr[w + 1] : 0.f;
            float a = bias + am * w0 + a0 * w1 + ap * w2
                           + bm * w3 + b0 * w4 + bp * w5
                           + cm * w6 + c0 * w7 + cp * w8;
            qk[ch][r][segw][tw] = a;
            am = bm; a0 = b0; ap = bp;
            bm = cm; b0 = c0; bp = cp;
        }
    }
    __syncthreads();

    const int row = tid >> 5;
    const int seg = (tid >> 3) & 3;
    const int i   = tid & 7;
    const int gr  = r0 + row;
    const int wp0 = seg * 64 + i * 8;

    const float* hbv = hidden + (size_t)(c + 2 * CQK) * HW;
    float4 hv[3][2];
    float  hm[3], hp[3];
    #pragma unroll
    for (int ky = 0; ky < 3; ++ky) {
        int grr = gr + ky - 1;
        hv[ky][0] = make_float4(0.f, 0.f, 0.f, 0.f);
        hv[ky][1] = make_float4(0.f, 0.f, 0.f, 0.f);
        hm[ky] = 0.f; hp[ky] = 0.f;
        if ((unsigned)grr < H_IMG) {
            const float* rb = hbv + (size_t)grr * W_IMG;
            hv[ky][0] = *reinterpret_cast<const float4*>(&rb[wp0]);
            hv[ky][1] = *reinterpret_cast<const float4*>(&rb[wp0 + 4]);
            hm[ky] = (wp0 > 0)   ? rb[wp0 - 1] : 0.f;
            hp[ky] = (wp0 < 248) ? rb[wp0 + 8] : 0.f;
        }
    }

    const float* qb = &qk[0][row][seg][0];
    const float* kb = &qk[1][row][seg][0];

    float acc[8];
    #pragma unroll
    for (int j = 0; j < 8; ++j) acc[j] = 0.f;

    #pragma unroll
    for (int s = 0; s < 8; ++s) {
        int qr = (i - s) & 7;
        float4 ka = *reinterpret_cast<const float4*>(&kb[s * 8]);
        float4 kc = *reinterpret_cast<const float4*>(&kb[s * 8 + 4]);
        float4 qa = *reinterpret_cast<const float4*>(&qb[qr * 8]);
        float4 qc = *reinterpret_cast<const float4*>(&qb[qr * 8 + 4]);
        float kr[8] = {ka.x, ka.y, ka.z, ka.w, kc.x, kc.y, kc.z, kc.w};
        float qv[8] = {qa.x, qa.y, qa.z, qa.w, qc.x, qc.y, qc.z, qc.w};
        #pragma unroll
        for (int t = 0; t < 8; ++t)
            #pragma unroll
            for (int j = 0; j < 8; ++j)
                acc[j] += kr[t] * qv[(j - t) & 7];
    }

    const float* wvv = wdw + (c + 2 * CQK) * 9;
    const float vbias = bdw[c + 2 * CQK];
    float vc[8];
    #pragma unroll
    for (int j = 0; j < 8; ++j) vc[j] = vbias;
    #pragma unroll
    for (int ky = 0; ky < 3; ++ky) {
        float kw0 = wvv[ky * 3], kw1 = wvv[ky * 3 + 1], kw2 = wvv[ky * 3 + 2];
        float h[10];
        h[0] = hm[ky];
        h[1] = hv[ky][0].x; h[2] = hv[ky][0].y; h[3] = hv[ky][0].z; h[4] = hv[ky][0].w;
        h[5] = hv[ky][1].x; h[6] = hv[ky][1].y; h[7] = hv[ky][1].z; h[8] = hv[ky][1].w;
        h[9] = hp[ky];
        #pragma unroll
        for (int j = 0; j < 8; ++j)
            vc[j] += h[j] * kw0 + h[j + 1] * kw1 + h[j + 2] * kw2;
    }

    float* dst = &vout[(size_t)c * HW + (size_t)gr * W_IMG + wp0];
    float4 o0, o1;
    o0.x = acc[0] * vc[0]; o0.y = acc[1] * vc[1];
    o0.z = acc[2] * vc[2]; o0.w = acc[3] * vc[3];
    o1.x = acc[4] * vc[4]; o1.y = acc[5] * vc[5];
    o1.z = acc[6] * vc[6]; o1.w = acc[7] * vc[7];
    *reinterpret_cast<float4*>(dst)     = o0;
    *reinterpret_cast<float4*>(dst + 4) = o1;
}

// ---------------- K3: 1x1 projection GEMM (LDS-free streaming) ----------------
// block = 64co x 256px, 4 waves; wave owns 16co x 256px; lane owns 16co x 4px.
__global__ __launch_bounds__(256) void k3_project(
    const float* __restrict__ vout_base,  // [B][CQK][HW]
    const float* __restrict__ wo,         // [64][CQK]
    const float* __restrict__ bo,         // [64]
    float* __restrict__ out_base,         // [B][64][HW]
    size_t vout_bstride, size_t out_bstride)
{
    const float* vout = vout_base + blockIdx.z * vout_bstride;
    float* out        = out_base + blockIdx.z * out_bstride;
    const int pxbase = blockIdx.x * 256;
    const int tid  = threadIdx.x;
    const int lane = tid & 63;
    const int wq   = __builtin_amdgcn_readfirstlane(tid >> 6);
    const int px   = pxbase + lane * 4;
    const int cw   = wq * 16;             // wave-uniform

    float acc[16][4];
    #pragma unroll
    for (int i = 0; i < 16; ++i)
        #pragma unroll
        for (int j = 0; j < 4; ++j) acc[i][j] = 0.f;

    #pragma unroll 2
    for (int cc4 = 0; cc4 < CQK; cc4 += 4) {
        float4 xv[4];
        #pragma unroll
        for (int u = 0; u < 4; ++u)
            xv[u] = *reinterpret_cast<const float4*>(&vout[(size_t)(cc4 + u) * HW + px]);
        #pragma unroll
        for (int i = 0; i < 16; ++i) {
            float4 wv = *reinterpret_cast<const float4*>(
                &wo[(size_t)(cw + i) * CQK + cc4]);   // uniform -> s_load
            float wu[4] = {wv.x, wv.y, wv.z, wv.w};
            #pragma unroll
            for (int u = 0; u < 4; ++u) {
                acc[i][0] += wu[u] * xv[u].x;
                acc[i][1] += wu[u] * xv[u].y;
                acc[i][2] += wu[u] * xv[u].z;
                acc[i][3] += wu[u] * xv[u].w;
            }
        }
    }

    #pragma unroll
    for (int i = 0; i < 16; ++i) {
        int co = cw + i;
        float b = bo[co];
        float4 o;
        o.x = acc[i][0] + b; o.y = acc[i][1] + b;
        o.z = acc[i][2] + b; o.w = acc[i][3] + b;
        *reinterpret_cast<float4*>(&out[(size_t)co * HW + px]) = o;
    }
}

extern "C" void kernel_launch(void* const* d_in, const int* in_sizes, int n_in,
                              void* d_out, int out_size, void* d_ws, size_t ws_size,
                              hipStream_t stream) {
    const float* x   = (const float*)d_in[0];
    const float* wh  = (const float*)d_in[1];
    const float* bh  = (const float*)d_in[2];
    const float* wdw = (const float*)d_in[3];
    const float* bdw = (const float*)d_in[4];
    const float* wo  = (const float*)d_in[5];
    const float* bo  = (const float*)d_in[6];
    float* out = (float*)d_out;

    const size_t n_hid  = (size_t)CHID * HW;
    const size_t n_vout = (size_t)CQK * HW;
    const size_t n_x    = (size_t)CIN * HW;

    if (ws_size >= 4 * (n_hid + n_vout) * sizeof(float)) {
        float* hidden = (float*)d_ws;
        float* vout   = hidden + 4 * n_hid;
        k1_expand <<<dim3(HW / 256, CHID / 64, 4), 256, 0, stream>>>(
            x, wh, bh, hidden, n_x, n_hid);
        k2_fused  <<<dim3(H_IMG / 8, CQK, 4),      256, 0, stream>>>(
            hidden, wdw, bdw, vout, n_hid, n_vout);
        k3_project<<<dim3(HW / 256, 1, 4),         256, 0, stream>>>(
            vout, wo, bo, out, n_vout, n_x);
    } else {
        float* hidden = (float*)d_ws;
        float* vout   = hidden + n_hid;
        for (int b = 0; b < 4; ++b) {
            const float* xb = x + (size_t)b * n_x;
            float* ob       = out + (size_t)b * n_x;
            k1_expand <<<dim3(HW / 256, CHID / 64, 1), 256, 0, stream>>>(
                xb, wh, bh, hidden, 0, 0);
            k2_fused  <<<dim3(H_IMG / 8, CQK, 1),      256, 0, stream>>>(
                hidden, wdw, bdw, vout, 0, 0);
            k3_project<<<dim3(HW / 256, 1, 1),         256, 0, stream>>>(
                vout, wo, bo, ob, 0, 0);
        }
    }
}

// Round 7
// 407.469 us; speedup vs baseline: 1.2336x; 1.0310x over previous
//
#include <hip/hip_runtime.h>

#define HW 65536
#define W_IMG 256
#define H_IMG 256
#define CIN 64
#define CHID 384
#define CQK 128

// ---------------- K1: 1x1 expansion GEMM (LDS-free streaming) ----------------
// block = 32co x 256px, 4 waves; wave owns 8co x 256px; lane owns 8co x 4px.
__global__ __launch_bounds__(256) void k1_expand(
    const float* __restrict__ x_base,    // [B][CIN][HW]
    const float* __restrict__ wh,        // [CHID][CIN]
    const float* __restrict__ bh,        // [CHID]
    float* __restrict__ hidden_base,     // [B][CHID][HW]
    size_t x_bstride, size_t hid_bstride)
{
    const float* x = x_base + blockIdx.z * x_bstride;
    float* hidden  = hidden_base + blockIdx.z * hid_bstride;
    const int pxbase = blockIdx.x * 256;
    const int cobase = blockIdx.y * 32;
    const int tid  = threadIdx.x;
    const int lane = tid & 63;
    const int wq   = __builtin_amdgcn_readfirstlane(tid >> 6);
    const int px   = pxbase + lane * 4;
    const int cw   = cobase + wq * 8;     // wave-uniform

    float acc[8][4];
    #pragma unroll
    for (int i = 0; i < 8; ++i)
        #pragma unroll
        for (int j = 0; j < 4; ++j) acc[i][j] = 0.f;

    #pragma unroll 2
    for (int ci4 = 0; ci4 < CIN; ci4 += 4) {
        float4 xv[4];
        #pragma unroll
        for (int u = 0; u < 4; ++u)
            xv[u] = *reinterpret_cast<const float4*>(&x[(size_t)(ci4 + u) * HW + px]);
        #pragma unroll
        for (int i = 0; i < 8; ++i) {
            // wave-uniform address -> s_load_dwordx4 (SGPR weights)
            float4 wv = *reinterpret_cast<const float4*>(
                &wh[(size_t)(cw + i) * CIN + ci4]);
            float wu[4] = {wv.x, wv.y, wv.z, wv.w};
            #pragma unroll
            for (int u = 0; u < 4; ++u) {
                acc[i][0] += wu[u] * xv[u].x;
                acc[i][1] += wu[u] * xv[u].y;
                acc[i][2] += wu[u] * xv[u].z;
                acc[i][3] += wu[u] * xv[u].w;
            }
        }
    }

    #pragma unroll
    for (int i = 0; i < 8; ++i) {
        int co = cw + i;
        float b = bh[co];
        float4 o;
        o.x = acc[i][0] + b; o.y = acc[i][1] + b;
        o.z = acc[i][2] + b; o.w = acc[i][3] + b;
        *reinterpret_cast<float4*>(&hidden[(size_t)co * HW + px]) = o;
    }
}

// ---------------- K2: fused depthwise 3x3 + 8x8 circular conv + v-mul ----------------
// v4: single-channel zero-padded staging buffer (27.9 KB LDS -> 5 blocks/CU),
//     no edge cndmasks in depthwise, v loads issued at kernel entry.
__global__ __launch_bounds__(256) void k2_fused(
    const float* __restrict__ hidden_base,  // [B][CHID][HW]
    const float* __restrict__ wdw,          // [CHID][9]
    const float* __restrict__ bdw,          // [CHID]
    float* __restrict__ vout_base,          // [B][CQK][HW]
    size_t hid_bstride, size_t vout_bstride)
{
    __shared__ float stg[10 * 264];      // one channel, rows r0-1..r0+8; pixel w at col w+4
    __shared__ float qk[2][8][4][68];    // depthwise q,k (padded strides)

    const float* hidden = hidden_base + blockIdx.z * hid_bstride;
    float* vout         = vout_base + blockIdx.z * vout_bstride;

    const int c  = blockIdx.y;
    const int r0 = blockIdx.x * 8;
    const int tid = threadIdx.x;

    const int row = tid >> 5;            // phase-2 ids (used for early v loads too)
    const int seg = (tid >> 3) & 3;
    const int i   = tid & 7;
    const int gr  = r0 + row;
    const int wp0 = seg * 64 + i * 8;

    // ---- issue v-channel global loads first: latency hides under phases 0/1
    const float* hbv = hidden + (size_t)(c + 2 * CQK) * HW;
    float4 hv[3][2];
    float  hm[3], hp[3];
    #pragma unroll
    for (int ky = 0; ky < 3; ++ky) {
        int grr = gr + ky - 1;
        hv[ky][0] = make_float4(0.f, 0.f, 0.f, 0.f);
        hv[ky][1] = make_float4(0.f, 0.f, 0.f, 0.f);
        hm[ky] = 0.f; hp[ky] = 0.f;
        if ((unsigned)grr < H_IMG) {
            const float* rb = hbv + (size_t)grr * W_IMG;
            hv[ky][0] = *reinterpret_cast<const float4*>(&rb[wp0]);
            hv[ky][1] = *reinterpret_cast<const float4*>(&rb[wp0 + 4]);
            hm[ky] = (wp0 > 0)   ? rb[wp0 - 1] : 0.f;
            hp[ky] = (wp0 < 248) ? rb[wp0 + 8] : 0.f;
        }
    }

    const int w = tid;
    const int segw = w >> 6;
    const int tw   = w & 63;

    // ---- per channel: stage (zero-padded) then depthwise from LDS
    #pragma unroll
    for (int ch = 0; ch < 2; ++ch) {
        if (ch) __syncthreads();         // dw(ch-1) finished reading stg
        // stage 10 rows x 256 px at col offset 4 (aligned float4)
        #pragma unroll
        for (int it = 0; it < 3; ++it) {
            int f4 = it * 256 + tid;     // 0..639
            if (f4 < 640) {
                int lr = f4 >> 6;
                int p4 = f4 & 63;
                int grr = r0 - 1 + lr;
                float4 v = make_float4(0.f, 0.f, 0.f, 0.f);
                if ((unsigned)grr < H_IMG)
                    v = *reinterpret_cast<const float4*>(
                        &hidden[(size_t)(c + ch * CQK) * HW + (size_t)grr * W_IMG + p4 * 4]);
                *reinterpret_cast<float4*>(&stg[lr * 264 + 4 + p4 * 4]) = v;
            }
        }
        if (tid < 10) {                  // zero halo columns (w-1 at col 3, w+1 at col 260)
            stg[tid * 264 + 3]   = 0.f;
            stg[tid * 264 + 260] = 0.f;
        }
        __syncthreads();

        const float* wv = wdw + (c + ch * CQK) * 9;   // block-uniform -> scalar loads
        const float bias = bdw[c + ch * CQK];
        const float w0 = wv[0], w1 = wv[1], w2 = wv[2];
        const float w3 = wv[3], w4 = wv[4], w5 = wv[5];
        const float w6 = wv[6], w7 = wv[7], w8 = wv[8];

        // register rotation over rows; no edge conditionals (padded zeros)
        const float* S0 = &stg[w + 3];
        float am = S0[0],       a0 = S0[1],       ap = S0[2];
        float bm = S0[264],     b0 = S0[265],     bp = S0[266];
        #pragma unroll
        for (int r = 0; r < 8; ++r) {
            const float* Sr = S0 + (r + 2) * 264;
            float cm = Sr[0], c0 = Sr[1], cp = Sr[2];
            float a = bias + am * w0 + a0 * w1 + ap * w2
                           + bm * w3 + b0 * w4 + bp * w5
                           + cm * w6 + c0 * w7 + cp * w8;
            qk[ch][r][segw][tw] = a;
            am = bm; a0 = b0; ap = bp;
            bm = cm; b0 = c0; bp = cp;
        }
    }
    __syncthreads();

    // ---- phase 2: 8x8 circular conv + v depthwise (from preloaded regs) + multiply
    const float* qb = &qk[0][row][seg][0];
    const float* kb = &qk[1][row][seg][0];

    float acc[8];
    #pragma unroll
    for (int j = 0; j < 8; ++j) acc[j] = 0.f;

    #pragma unroll
    for (int s = 0; s < 8; ++s) {
        int qr = (i - s) & 7;
        float4 ka = *reinterpret_cast<const float4*>(&kb[s * 8]);
        float4 kc = *reinterpret_cast<const float4*>(&kb[s * 8 + 4]);
        float4 qa = *reinterpret_cast<const float4*>(&qb[qr * 8]);
        float4 qc = *reinterpret_cast<const float4*>(&qb[qr * 8 + 4]);
        float kr[8] = {ka.x, ka.y, ka.z, ka.w, kc.x, kc.y, kc.z, kc.w};
        float qv[8] = {qa.x, qa.y, qa.z, qa.w, qc.x, qc.y, qc.z, qc.w};
        #pragma unroll
        for (int t = 0; t < 8; ++t)
            #pragma unroll
            for (int j = 0; j < 8; ++j)
                acc[j] += kr[t] * qv[(j - t) & 7];
    }

    const float* wvv = wdw + (c + 2 * CQK) * 9;
    const float vbias = bdw[c + 2 * CQK];
    float vc[8];
    #pragma unroll
    for (int j = 0; j < 8; ++j) vc[j] = vbias;
    #pragma unroll
    for (int ky = 0; ky < 3; ++ky) {
        float kw0 = wvv[ky * 3], kw1 = wvv[ky * 3 + 1], kw2 = wvv[ky * 3 + 2];
        float h[10];
        h[0] = hm[ky];
        h[1] = hv[ky][0].x; h[2] = hv[ky][0].y; h[3] = hv[ky][0].z; h[4] = hv[ky][0].w;
        h[5] = hv[ky][1].x; h[6] = hv[ky][1].y; h[7] = hv[ky][1].z; h[8] = hv[ky][1].w;
        h[9] = hp[ky];
        #pragma unroll
        for (int j = 0; j < 8; ++j)
            vc[j] += h[j] * kw0 + h[j + 1] * kw1 + h[j + 2] * kw2;
    }

    float* dst = &vout[(size_t)c * HW + (size_t)gr * W_IMG + wp0];
    float4 o0, o1;
    o0.x = acc[0] * vc[0]; o0.y = acc[1] * vc[1];
    o0.z = acc[2] * vc[2]; o0.w = acc[3] * vc[3];
    o1.x = acc[4] * vc[4]; o1.y = acc[5] * vc[5];
    o1.z = acc[6] * vc[6]; o1.w = acc[7] * vc[7];
    *reinterpret_cast<float4*>(dst)     = o0;
    *reinterpret_cast<float4*>(dst + 4) = o1;
}

// ---------------- K3: 1x1 projection GEMM (LDS-free streaming) ----------------
// block = 16co x 256px, 4 waves; wave owns 4co x 256px; lane owns 4co x 4px.
__global__ __launch_bounds__(256) void k3_project(
    const float* __restrict__ vout_base,  // [B][CQK][HW]
    const float* __restrict__ wo,         // [64][CQK]
    const float* __restrict__ bo,         // [64]
    float* __restrict__ out_base,         // [B][64][HW]
    size_t vout_bstride, size_t out_bstride)
{
    const float* vout = vout_base + blockIdx.z * vout_bstride;
    float* out        = out_base + blockIdx.z * out_bstride;
    const int pxbase = blockIdx.x * 256;
    const int cobase = blockIdx.y * 16;
    const int tid  = threadIdx.x;
    const int lane = tid & 63;
    const int wq   = __builtin_amdgcn_readfirstlane(tid >> 6);
    const int px   = pxbase + lane * 4;
    const int cw   = cobase + wq * 4;     // wave-uniform

    float acc[4][4];
    #pragma unroll
    for (int i = 0; i < 4; ++i)
        #pragma unroll
        for (int j = 0; j < 4; ++j) acc[i][j] = 0.f;

    #pragma unroll 2
    for (int cc4 = 0; cc4 < CQK; cc4 += 4) {
        float4 xv[4];
        #pragma unroll
        for (int u = 0; u < 4; ++u)
            xv[u] = *reinterpret_cast<const float4*>(&vout[(size_t)(cc4 + u) * HW + px]);
        #pragma unroll
        for (int i = 0; i < 4; ++i) {
            float4 wv = *reinterpret_cast<const float4*>(
                &wo[(size_t)(cw + i) * CQK + cc4]);   // uniform -> s_load
            float wu[4] = {wv.x, wv.y, wv.z, wv.w};
            #pragma unroll
            for (int u = 0; u < 4; ++u) {
                acc[i][0] += wu[u] * xv[u].x;
                acc[i][1] += wu[u] * xv[u].y;
                acc[i][2] += wu[u] * xv[u].z;
                acc[i][3] += wu[u] * xv[u].w;
            }
        }
    }

    #pragma unroll
    for (int i = 0; i < 4; ++i) {
        int co = cw + i;
        float b = bo[co];
        float4 o;
        o.x = acc[i][0] + b; o.y = acc[i][1] + b;
        o.z = acc[i][2] + b; o.w = acc[i][3] + b;
        *reinterpret_cast<float4*>(&out[(size_t)co * HW + px]) = o;
    }
}

extern "C" void kernel_launch(void* const* d_in, const int* in_sizes, int n_in,
                              void* d_out, int out_size, void* d_ws, size_t ws_size,
                              hipStream_t stream) {
    const float* x   = (const float*)d_in[0];
    const float* wh  = (const float*)d_in[1];
    const float* bh  = (const float*)d_in[2];
    const float* wdw = (const float*)d_in[3];
    const float* bdw = (const float*)d_in[4];
    const float* wo  = (const float*)d_in[5];
    const float* bo  = (const float*)d_in[6];
    float* out = (float*)d_out;

    const size_t n_hid  = (size_t)CHID * HW;
    const size_t n_vout = (size_t)CQK * HW;
    const size_t n_x    = (size_t)CIN * HW;

    if (ws_size >= 4 * (n_hid + n_vout) * sizeof(float)) {
        float* hidden = (float*)d_ws;
        float* vout   = hidden + 4 * n_hid;
        k1_expand <<<dim3(HW / 256, CHID / 32, 4), 256, 0, stream>>>(
            x, wh, bh, hidden, n_x, n_hid);
        k2_fused  <<<dim3(H_IMG / 8, CQK, 4),      256, 0, stream>>>(
            hidden, wdw, bdw, vout, n_hid, n_vout);
        k3_project<<<dim3(HW / 256, 64 / 16, 4),   256, 0, stream>>>(
            vout, wo, bo, out, n_vout, n_x);
    } else {
        float* hidden = (float*)d_ws;
        float* vout   = hidden + n_hid;
        for (int b = 0; b < 4; ++b) {
            const float* xb = x + (size_t)b * n_x;
            float* ob       = out + (size_t)b * n_x;
            k1_expand <<<dim3(HW / 256, CHID / 32, 1), 256, 0, stream>>>(
                xb, wh, bh, hidden, 0, 0);
            k2_fused  <<<dim3(H_IMG / 8, CQK, 1),      256, 0, stream>>>(
                hidden, wdw, bdw, vout, 0, 0);
            k3_project<<<dim3(HW / 256, 64 / 16, 1),   256, 0, stream>>>(
                vout, wo, bo, ob, 0, 0);
        }
    }
}

// Round 8
// 403.793 us; speedup vs baseline: 1.2448x; 1.0091x over previous
//
#include <hip/hip_runtime.h>

#define HW 65536
#define W_IMG 256
#define H_IMG 256
#define CIN 64
#define CHID 384
#define CQK 128

// ---------------- K1: 1x1 expansion GEMM (LDS-free streaming) ----------------
// block = 48co x 256px, 4 waves; wave owns 12co x 256px; lane owns 12co x 4px.
// grid = 256 x 8 = 2048 blocks = exactly 8 blocks/CU (no residency tail).
__global__ __launch_bounds__(256) void k1_expand(
    const float* __restrict__ x_base,    // [B][CIN][HW]
    const float* __restrict__ wh,        // [CHID][CIN]
    const float* __restrict__ bh,        // [CHID]
    float* __restrict__ hidden_base,     // [B][CHID][HW]
    size_t x_bstride, size_t hid_bstride)
{
    const float* x = x_base + blockIdx.z * x_bstride;
    float* hidden  = hidden_base + blockIdx.z * hid_bstride;
    const int pxbase = blockIdx.x * 256;
    const int cobase = blockIdx.y * 48;
    const int tid  = threadIdx.x;
    const int lane = tid & 63;
    const int wq   = __builtin_amdgcn_readfirstlane(tid >> 6);
    const int px   = pxbase + lane * 4;
    const int cw   = cobase + wq * 12;    // wave-uniform

    float acc[12][4];
    #pragma unroll
    for (int i = 0; i < 12; ++i)
        #pragma unroll
        for (int j = 0; j < 4; ++j) acc[i][j] = 0.f;

    #pragma unroll 2
    for (int ci4 = 0; ci4 < CIN; ci4 += 4) {
        float4 xv[4];
        #pragma unroll
        for (int u = 0; u < 4; ++u)
            xv[u] = *reinterpret_cast<const float4*>(&x[(size_t)(ci4 + u) * HW + px]);
        #pragma unroll
        for (int i = 0; i < 12; ++i) {
            // wave-uniform address -> s_load_dwordx4 (SGPR weights)
            float4 wv = *reinterpret_cast<const float4*>(
                &wh[(size_t)(cw + i) * CIN + ci4]);
            float wu[4] = {wv.x, wv.y, wv.z, wv.w};
            #pragma unroll
            for (int u = 0; u < 4; ++u) {
                acc[i][0] += wu[u] * xv[u].x;
                acc[i][1] += wu[u] * xv[u].y;
                acc[i][2] += wu[u] * xv[u].z;
                acc[i][3] += wu[u] * xv[u].w;
            }
        }
    }

    #pragma unroll
    for (int i = 0; i < 12; ++i) {
        int co = cw + i;
        float b = bh[co];
        float4 o;
        o.x = acc[i][0] + b; o.y = acc[i][1] + b;
        o.z = acc[i][2] + b; o.w = acc[i][3] + b;
        *reinterpret_cast<float4*>(&hidden[(size_t)co * HW + px]) = o;
    }
}

// ---------------- K2: fused depthwise 3x3 + 8x8 circular conv + v-mul ----------------
// v5: qk row stride 276 floats (69 f4) -> phase-2 q-read bank multiplicity <= 2-way (free).
#define QK_CH   2208   // 8*276 floats
#define QK_ROW  276    // 69 float4
#define QK_SEG  68     // 17 float4
__global__ __launch_bounds__(256) void k2_fused(
    const float* __restrict__ hidden_base,  // [B][CHID][HW]
    const float* __restrict__ wdw,          // [CHID][9]
    const float* __restrict__ bdw,          // [CHID]
    float* __restrict__ vout_base,          // [B][CQK][HW]
    size_t hid_bstride, size_t vout_bstride)
{
    __shared__ float stg[10 * 264];      // one channel, rows r0-1..r0+8; pixel w at col w+4
    __shared__ float qk[2 * QK_CH];      // depthwise q,k

    const float* hidden = hidden_base + blockIdx.z * hid_bstride;
    float* vout         = vout_base + blockIdx.z * vout_bstride;

    const int c  = blockIdx.y;
    const int r0 = blockIdx.x * 8;
    const int tid = threadIdx.x;

    const int row = tid >> 5;            // phase-2 ids (used for early v loads too)
    const int seg = (tid >> 3) & 3;
    const int i   = tid & 7;
    const int gr  = r0 + row;
    const int wp0 = seg * 64 + i * 8;

    // ---- issue v-channel global loads first: latency hides under phases 0/1
    const float* hbv = hidden + (size_t)(c + 2 * CQK) * HW;
    float4 hv[3][2];
    float  hm[3], hp[3];
    #pragma unroll
    for (int ky = 0; ky < 3; ++ky) {
        int grr = gr + ky - 1;
        hv[ky][0] = make_float4(0.f, 0.f, 0.f, 0.f);
        hv[ky][1] = make_float4(0.f, 0.f, 0.f, 0.f);
        hm[ky] = 0.f; hp[ky] = 0.f;
        if ((unsigned)grr < H_IMG) {
            const float* rb = hbv + (size_t)grr * W_IMG;
            hv[ky][0] = *reinterpret_cast<const float4*>(&rb[wp0]);
            hv[ky][1] = *reinterpret_cast<const float4*>(&rb[wp0 + 4]);
            hm[ky] = (wp0 > 0)   ? rb[wp0 - 1] : 0.f;
            hp[ky] = (wp0 < 248) ? rb[wp0 + 8] : 0.f;
        }
    }

    const int w = tid;
    const int segw = w >> 6;
    const int tw   = w & 63;

    // ---- per channel: stage (zero-padded) then depthwise from LDS
    #pragma unroll
    for (int ch = 0; ch < 2; ++ch) {
        if (ch) __syncthreads();         // dw(ch-1) finished reading stg
        // stage 10 rows x 256 px at col offset 4 (aligned float4)
        #pragma unroll
        for (int it = 0; it < 3; ++it) {
            int f4 = it * 256 + tid;     // 0..639
            if (f4 < 640) {
                int lr = f4 >> 6;
                int p4 = f4 & 63;
                int grr = r0 - 1 + lr;
                float4 v = make_float4(0.f, 0.f, 0.f, 0.f);
                if ((unsigned)grr < H_IMG)
                    v = *reinterpret_cast<const float4*>(
                        &hidden[(size_t)(c + ch * CQK) * HW + (size_t)grr * W_IMG + p4 * 4]);
                *reinterpret_cast<float4*>(&stg[lr * 264 + 4 + p4 * 4]) = v;
            }
        }
        if (tid < 10) {                  // zero halo columns (w-1 at col 3, w+1 at col 260)
            stg[tid * 264 + 3]   = 0.f;
            stg[tid * 264 + 260] = 0.f;
        }
        __syncthreads();

        const float* wv = wdw + (c + ch * CQK) * 9;   // block-uniform -> scalar loads
        const float bias = bdw[c + ch * CQK];
        const float w0 = wv[0], w1 = wv[1], w2 = wv[2];
        const float w3 = wv[3], w4 = wv[4], w5 = wv[5];
        const float w6 = wv[6], w7 = wv[7], w8 = wv[8];

        // register rotation over rows; no edge conditionals (padded zeros)
        const float* S0 = &stg[w + 3];
        float am = S0[0],       a0 = S0[1],       ap = S0[2];
        float bm = S0[264],     b0 = S0[265],     bp = S0[266];
        #pragma unroll
        for (int r = 0; r < 8; ++r) {
            const float* Sr = S0 + (r + 2) * 264;
            float cm = Sr[0], c0 = Sr[1], cp = Sr[2];
            float a = bias + am * w0 + a0 * w1 + ap * w2
                           + bm * w3 + b0 * w4 + bp * w5
                           + cm * w6 + c0 * w7 + cp * w8;
            qk[ch * QK_CH + r * QK_ROW + segw * QK_SEG + tw] = a;
            am = bm; a0 = b0; ap = bp;
            bm = cm; b0 = c0; bp = cp;
        }
    }
    __syncthreads();

    // ---- phase 2: 8x8 circular conv + v depthwise (from preloaded regs) + multiply
    const float* qb = &qk[row * QK_ROW + seg * QK_SEG];
    const float* kb = &qk[QK_CH + row * QK_ROW + seg * QK_SEG];

    float acc[8];
    #pragma unroll
    for (int j = 0; j < 8; ++j) acc[j] = 0.f;

    #pragma unroll
    for (int s = 0; s < 8; ++s) {
        int qr = (i - s) & 7;
        float4 ka = *reinterpret_cast<const float4*>(&kb[s * 8]);
        float4 kc = *reinterpret_cast<const float4*>(&kb[s * 8 + 4]);
        float4 qa = *reinterpret_cast<const float4*>(&qb[qr * 8]);
        float4 qc = *reinterpret_cast<const float4*>(&qb[qr * 8 + 4]);
        float kr[8] = {ka.x, ka.y, ka.z, ka.w, kc.x, kc.y, kc.z, kc.w};
        float qv[8] = {qa.x, qa.y, qa.z, qa.w, qc.x, qc.y, qc.z, qc.w};
        #pragma unroll
        for (int t = 0; t < 8; ++t)
            #pragma unroll
            for (int j = 0; j < 8; ++j)
                acc[j] += kr[t] * qv[(j - t) & 7];
    }

    const float* wvv = wdw + (c + 2 * CQK) * 9;
    const float vbias = bdw[c + 2 * CQK];
    float vc[8];
    #pragma unroll
    for (int j = 0; j < 8; ++j) vc[j] = vbias;
    #pragma unroll
    for (int ky = 0; ky < 3; ++ky) {
        float kw0 = wvv[ky * 3], kw1 = wvv[ky * 3 + 1], kw2 = wvv[ky * 3 + 2];
        float h[10];
        h[0] = hm[ky];
        h[1] = hv[ky][0].x; h[2] = hv[ky][0].y; h[3] = hv[ky][0].z; h[4] = hv[ky][0].w;
        h[5] = hv[ky][1].x; h[6] = hv[ky][1].y; h[7] = hv[ky][1].z; h[8] = hv[ky][1].w;
        h[9] = hp[ky];
        #pragma unroll
        for (int j = 0; j < 8; ++j)
            vc[j] += h[j] * kw0 + h[j + 1] * kw1 + h[j + 2] * kw2;
    }

    float* dst = &vout[(size_t)c * HW + (size_t)gr * W_IMG + wp0];
    float4 o0, o1;
    o0.x = acc[0] * vc[0]; o0.y = acc[1] * vc[1];
    o0.z = acc[2] * vc[2]; o0.w = acc[3] * vc[3];
    o1.x = acc[4] * vc[4]; o1.y = acc[5] * vc[5];
    o1.z = acc[6] * vc[6]; o1.w = acc[7] * vc[7];
    *reinterpret_cast<float4*>(dst)     = o0;
    *reinterpret_cast<float4*>(dst + 4) = o1;
}

// ---------------- K3: 1x1 projection GEMM (LDS-free streaming) ----------------
// block = 16co x 256px, 4 waves; wave owns 4co x 256px; lane owns 4co x 4px.
__global__ __launch_bounds__(256) void k3_project(
    const float* __restrict__ vout_base,  // [B][CQK][HW]
    const float* __restrict__ wo,         // [64][CQK]
    const float* __restrict__ bo,         // [64]
    float* __restrict__ out_base,         // [B][64][HW]
    size_t vout_bstride, size_t out_bstride)
{
    const float* vout = vout_base + blockIdx.z * vout_bstride;
    float* out        = out_base + blockIdx.z * out_bstride;
    const int pxbase = blockIdx.x * 256;
    const int cobase = blockIdx.y * 16;
    const int tid  = threadIdx.x;
    const int lane = tid & 63;
    const int wq   = __builtin_amdgcn_readfirstlane(tid >> 6);
    const int px   = pxbase + lane * 4;
    const int cw   = cobase + wq * 4;     // wave-uniform

    float acc[4][4];
    #pragma unroll
    for (int i = 0; i < 4; ++i)
        #pragma unroll
        for (int j = 0; j < 4; ++j) acc[i][j] = 0.f;

    #pragma unroll 2
    for (int cc4 = 0; cc4 < CQK; cc4 += 4) {
        float4 xv[4];
        #pragma unroll
        for (int u = 0; u < 4; ++u)
            xv[u] = *reinterpret_cast<const float4*>(&vout[(size_t)(cc4 + u) * HW + px]);
        #pragma unroll
        for (int i = 0; i < 4; ++i) {
            float4 wv = *reinterpret_cast<const float4*>(
                &wo[(size_t)(cw + i) * CQK + cc4]);   // uniform -> s_load
            float wu[4] = {wv.x, wv.y, wv.z, wv.w};
            #pragma unroll
            for (int u = 0; u < 4; ++u) {
                acc[i][0] += wu[u] * xv[u].x;
                acc[i][1] += wu[u] * xv[u].y;
                acc[i][2] += wu[u] * xv[u].z;
                acc[i][3] += wu[u] * xv[u].w;
            }
        }
    }

    #pragma unroll
    for (int i = 0; i < 4; ++i) {
        int co = cw + i;
        float b = bo[co];
        float4 o;
        o.x = acc[i][0] + b; o.y = acc[i][1] + b;
        o.z = acc[i][2] + b; o.w = acc[i][3] + b;
        *reinterpret_cast<float4*>(&out[(size_t)co * HW + px]) = o;
    }
}

extern "C" void kernel_launch(void* const* d_in, const int* in_sizes, int n_in,
                              void* d_out, int out_size, void* d_ws, size_t ws_size,
                              hipStream_t stream) {
    const float* x   = (const float*)d_in[0];
    const float* wh  = (const float*)d_in[1];
    const float* bh  = (const float*)d_in[2];
    const float* wdw = (const float*)d_in[3];
    const float* bdw = (const float*)d_in[4];
    const float* wo  = (const float*)d_in[5];
    const float* bo  = (const float*)d_in[6];
    float* out = (float*)d_out;

    const size_t n_hid  = (size_t)CHID * HW;
    const size_t n_vout = (size_t)CQK * HW;
    const size_t n_x    = (size_t)CIN * HW;

    if (ws_size >= 4 * (n_hid + n_vout) * sizeof(float)) {
        float* hidden = (float*)d_ws;
        float* vout   = hidden + 4 * n_hid;
        k1_expand <<<dim3(HW / 256, CHID / 48, 4), 256, 0, stream>>>(
            x, wh, bh, hidden, n_x, n_hid);
        k2_fused  <<<dim3(H_IMG / 8, CQK, 4),      256, 0, stream>>>(
            hidden, wdw, bdw, vout, n_hid, n_vout);
        k3_project<<<dim3(HW / 256, 64 / 16, 4),   256, 0, stream>>>(
            vout, wo, bo, out, n_vout, n_x);
    } else {
        float* hidden = (float*)d_ws;
        float* vout   = hidden + n_hid;
        for (int b = 0; b < 4; ++b) {
            const float* xb = x + (size_t)b * n_x;
            float* ob       = out + (size_t)b * n_x;
            k1_expand <<<dim3(HW / 256, CHID / 48, 1), 256, 0, stream>>>(
                xb, wh, bh, hidden, 0, 0);
            k2_fused  <<<dim3(H_IMG / 8, CQK, 1),      256, 0, stream>>>(
                hidden, wdw, bdw, vout, 0, 0);
            k3_project<<<dim3(HW / 256, 64 / 16, 1),   256, 0, stream>>>(
                vout, wo, bo, ob, 0, 0);
        }
    }
}